// Round 5
// baseline (1758.481 us; speedup 1.0000x reference)
//
#include <hip/hip_runtime.h>

// PGA joint com/radar beamforming, K=8 B=64 M=8 NT=64 NRF=8, 10 iters.
// One persistent kernel: 512 blocks (one per (k,b)) x 256 threads, all
// co-resident (launch_bounds(256,2) -> >=2 blocks/CU -> 512 slots == grid).
// OUTPUT (d_out, float32, 296320 elems): rates[64][11] | taus[64][11] |
//   Re(F)[K,B,64,8] | Re(W)[K,B,8,8]  (harness stores real parts only).
// Cross-k F-gradient mean exchanged through the F_re/F_im INPUT buffers
// (each block's own (k,b) slice is dead after the initial proj_unit read;
// harness restores d_in before every timed launch). Per-b 8-block spin
// barrier (agent-scope atomics) twice per iteration (write-ready/read-done).
// d_ws: only 64 barrier counters (<=4KB, clamped to ws_size).
// R held permanently in registers (16 cplx/thread); RF = R@F computed once
// per iteration, reused by grad_F_rad, grad_W_rad, beam_err.

typedef float2 cplx;

#define LN2F 0.69314718055994530942f

__device__ __forceinline__ cplx mkc(float x, float y){ return make_float2(x, y); }

__device__ __forceinline__ void cfma (cplx& a, cplx b, cplx c){            // a += b*c
  a.x = fmaf(b.x, c.x, a.x); a.x = fmaf(-b.y, c.y, a.x);
  a.y = fmaf(b.x, c.y, a.y); a.y = fmaf( b.y, c.x, a.y);
}
__device__ __forceinline__ void cfmac(cplx& a, cplx b, cplx c){            // a += conj(b)*c
  a.x = fmaf(b.x, c.x, a.x); a.x = fmaf( b.y, c.y, a.x);
  a.y = fmaf(b.x, c.y, a.y); a.y = fmaf(-b.y, c.x, a.y);
}
__device__ __forceinline__ void cfmacj(cplx& a, cplx b, cplx c){           // a += b*conj(c)
  a.x = fmaf(b.x, c.x, a.x); a.x = fmaf( b.y, c.y, a.x);
  a.y = fmaf(-b.x, c.y, a.y); a.y = fmaf( b.y, c.x, a.y);
}
__device__ __forceinline__ cplx cmuljc(cplx b, cplx c){                    // b*conj(c)
  return mkc(b.x*c.x + b.y*c.y, b.y*c.x - b.x*c.y);
}

// agent-scope 4B stores/loads for the cross-XCD P exchange
__device__ __forceinline__ void storePf(float* p, float v){
  __hip_atomic_store(p, v, __ATOMIC_RELAXED, __HIP_MEMORY_SCOPE_AGENT);
}
__device__ __forceinline__ float loadPf(const float* p){
  return __hip_atomic_load(p, __ATOMIC_RELAXED, __HIP_MEMORY_SCOPE_AGENT);
}

__device__ __forceinline__ float blockSum(float v, float* sred, int tid){
  #pragma unroll
  for (int off = 32; off > 0; off >>= 1) v += __shfl_down(v, off, 64);
  __syncthreads();                       // protect sred reuse
  if ((tid & 63) == 0) sred[tid >> 6] = v;
  __syncthreads();
  return sred[0] + sred[1] + sred[2] + sred[3];
}

// OUT[q][n] = sum_s IN[s][n] * (TR ? SM[q][s] : SM[s][q]); q = 2w,2w+1, n = lane
template<bool TR>
__device__ __forceinline__ void type2r(const cplx* __restrict__ IN, const cplx* __restrict__ SM,
                                       int tid, cplx& o0, cplx& o1){
  const int n = tid & 63, w = tid >> 6;
  const int q0 = 2*w, q1 = 2*w + 1;
  cplx a = mkc(0.f,0.f), b = mkc(0.f,0.f);
  #pragma unroll
  for (int s = 0; s < 8; ++s){
    cplx in = IN[s*66 + n];
    cplx m0 = TR ? SM[q0*9 + s] : SM[s*9 + q0];
    cplx m1 = TR ? SM[q1*9 + s] : SM[s*9 + q1];
    cfma(a, in, m0);
    cfma(b, in, m1);
  }
  o0 = a; o1 = b;
}

template<bool TR>
__device__ __forceinline__ void type2s(const cplx* IN, const cplx* SM, cplx* OUT, int tid){
  cplx o0, o1;
  type2r<TR>(IN, SM, tid, o0, o1);
  const int n = tid & 63, w = tid >> 6;
  OUT[(2*w)*66 + n]   = o0;
  OUT[(2*w+1)*66 + n] = o1;
}

// partial of O[p][q] = sum_n conj(P1[p][n]) * P2[q][n] over n in [16c,16c+16)
__device__ __forceinline__ cplx type3part(const cplx* __restrict__ P1, const cplx* __restrict__ P2, int tid){
  const int p = (tid >> 3) & 7, q = tid & 7, c = tid >> 6;
  const int n0 = c * 16;
  cplx a = mkc(0.f,0.f);
  #pragma unroll
  for (int nn = 0; nn < 16; ++nn){
    cfmac(a, P1[p*66 + n0 + nn], P2[q*66 + n0 + nn]);
  }
  return a;
}

__device__ __forceinline__ void t3gather(cplx* d0, cplx* d1, cplx* d2, int nops,
                                         const cplx* scr, int tid){
  if (tid < nops*64){
    int op = tid >> 6, pq = tid & 63;
    cplx a = scr[(0*nops+op)*64 + pq];
    cplx b = scr[(1*nops+op)*64 + pq];
    cplx c = scr[(2*nops+op)*64 + pq];
    cplx d = scr[(3*nops+op)*64 + pq];
    cplx r = mkc(a.x+b.x+c.x+d.x, a.y+b.y+c.y+d.y);
    cplx* dst = (op == 0) ? d0 : (op == 1) ? d1 : d2;
    dst[(pq>>3)*9 + (pq&7)] = r;
  }
}

// RF = R @ F using register-resident R tiles. Each thread (wave w, lane l):
// rows (l&31, (l&31)+32), j in [16w + 8*(l>>5), +8). scr >= 1152 cplx.
__device__ __forceinline__ void computeRF(const cplx* Rreg, const cplx* sF_, cplx* sRF_,
                                          cplx* scr, int tid){
  const int l = tid & 63, w = tid >> 6;
  const int half = l >> 5;
  const int j0 = w*16 + half*8;
  cplx acc[16];
  #pragma unroll
  for (int q = 0; q < 16; ++q) acc[q] = mkc(0.f,0.f);
  #pragma unroll
  for (int jj = 0; jj < 8; ++jj){
    const int j = j0 + jj;
    cplx Ra = Rreg[2*jj], Rb = Rreg[2*jj+1];
    #pragma unroll
    for (int r = 0; r < 8; ++r){
      cplx f = sF_[r*66 + j];              // wave-broadcast (2 addrs) - free
      cfma(acc[r],   Ra, f);
      cfma(acc[8+r], Rb, f);
    }
  }
  #pragma unroll
  for (int q = 0; q < 16; ++q){            // combine j-halves (lanes l <-> l^32)
    acc[q].x += __shfl_xor(acc[q].x, 32, 64);
    acc[q].y += __shfl_xor(acc[q].y, 32, 64);
  }
  const int row = (half == 0) ? (l & 31) : ((l & 31) + 32);
  const int off = half ? 8 : 0;
  __syncthreads();                         // protect scr
  if (w < 2){
    #pragma unroll
    for (int r = 0; r < 8; ++r) scr[w*576 + row*9 + r] = acc[off + r];
  }
  __syncthreads();
  if (w >= 2){
    const int base = (w-2)*576 + row*9;
    #pragma unroll
    for (int r = 0; r < 8; ++r){
      cplx t = scr[base + r];
      t.x += acc[off + r].x; t.y += acc[off + r].y;
      scr[base + r] = t;
    }
  }
  __syncthreads();
  #pragma unroll
  for (int o0 = 0; o0 < 2; ++o0){
    const int o = tid + o0*256;
    const int r = o >> 6, n = o & 63;
    cplx a = scr[n*9 + r], b = scr[576 + n*9 + r];
    sRF_[r*66 + n] = mkc(a.x + b.x, a.y + b.y);
  }
}

// per-b barrier among the 8 k-blocks (monotonic counter, no reset)
__device__ __forceinline__ void groupBarrier(unsigned* cnt, unsigned target, int tid){
  __threadfence();
  __syncthreads();
  if (tid == 0){
    __hip_atomic_fetch_add(cnt, 1u, __ATOMIC_ACQ_REL, __HIP_MEMORY_SCOPE_AGENT);
    while (__hip_atomic_load(cnt, __ATOMIC_ACQUIRE, __HIP_MEMORY_SCOPE_AGENT) < target){
      __builtin_amdgcn_s_sleep(2);
    }
    __threadfence();
  }
  __syncthreads();
}

__global__ __launch_bounds__(256, 2)
void pga_fused_kernel(const float* __restrict__ H_re, const float* __restrict__ H_im,
                      const float* __restrict__ R_re, const float* __restrict__ R_im,
                      float* __restrict__ F_re, float* __restrict__ F_im,
                      const float* __restrict__ W_re, const float* __restrict__ W_im,
                      const float* __restrict__ step_g, const int* __restrict__ PtA,
                      float* __restrict__ out, unsigned* __restrict__ bcnt,
                      int cstride)
{
  const int bid = blockIdx.x;
  const int kk = bid >> 6;             // subcarrier
  const int bb = bid & 63;             // batch
  const int tid = threadIdx.x;
  const int l = tid & 63, w = tid >> 6;
  const size_t kb = (size_t)(kk*64 + bb);

  __shared__ cplx sF [528];            // [8][66]: sF[r][n] = F[n][r]
  __shared__ cplx sT [528];            // FV / FW temp
  __shared__ cplx sRF[528];            // R@F
  __shared__ cplx sH [528];            // H[m][n]
  __shared__ cplx sml[13*72];          // 8x8 mats, [p*9+q]
  __shared__ cplx scr[1152];           // reductions
  __shared__ float sD1[8], sD2[8], sredm[8];
  __shared__ cplx sSm[8];

  cplx* sW  = sml + 0*72;
  cplx* sV  = sml + 1*72;
  cplx* sG  = sml + 2*72;   // g stored transposed: sG[r*9+m] = g[m][r]
  cplx* sA1 = sml + 3*72;
  cplx* sX  = sml + 4*72;
  cplx* sC  = sml + 5*72;
  cplx* sU  = sml + 6*72;
  cplx* sGWC= sml + 7*72;
  cplx* sTM = sml + 8*72;
  cplx* sA2 = sml + 9*72;
  cplx* sB2 = sml + 10*72;
  cplx* sC1 = sml + 11*72;
  cplx* sG2 = sml + 12*72;

  float* out_rates = out;              // [64][11]
  float* out_taus  = out + 704;       // [64][11]
  float* out_F = out + 1408;          // Re(F) [K,B,64,8]
  float* out_W = out + 1408 + 262144; // Re(W) [K,B,8,8]

  // P-exchange scratch: this block's own 512-float slices of F_re / F_im
  // (inputs are dead after the initial proj_unit read; restored by harness)
  float* PexRe = F_re;
  float* PexIm = F_im;

  unsigned* cnt = bcnt + bb*cstride;

  const float* Hre = H_re + kb*512;
  const float* Him = H_im + kb*512;
  const float* Fre = F_re + kb*512;
  const float* Fim = F_im + kb*512;
  const float* Wre = W_re + kb*64;
  const float* Wim = W_im + kb*64;
  const float* Rre = R_re + kb*4096;
  const float* Rim = R_im + kb*4096;

  // ---------- loads ----------
  #pragma unroll
  for (int o0 = 0; o0 < 2; ++o0){
    int o = tid + o0*256;
    int m = o >> 6, n = o & 63;
    sH[m*66 + n] = mkc(Hre[m*64 + n], Him[m*64 + n]);
  }
  #pragma unroll
  for (int o0 = 0; o0 < 2; ++o0){
    int o = tid + o0*256;
    int n = o >> 3, r = o & 7;
    float fr = Fre[n*8 + r], fi = Fim[n*8 + r];
    float mag = sqrtf(fr*fr + fi*fi);
    cplx v = (mag > 1e-12f) ? mkc(fr/mag, fi/mag) : mkc(0.f,0.f);   // proj_unit
    sF[r*66 + n] = v;
  }
  if (tid < 64) sW[(tid>>3)*9 + (tid&7)] = mkc(Wre[tid], Wim[tid]);

  // R tiles -> registers, + ||R_kb||^2 partial
  cplx Rreg[16];
  float rnp = 0.f;
  {
    const int rA = l & 31, rB = rA + 32;
    const int j0 = w*16 + (l >> 5)*8;
    const float4* a0 = (const float4*)(Rre + rA*64 + j0);
    const float4* a1 = (const float4*)(Rim + rA*64 + j0);
    const float4* b0 = (const float4*)(Rre + rB*64 + j0);
    const float4* b1 = (const float4*)(Rim + rB*64 + j0);
    float4 xr0 = a0[0], xr1 = a0[1], xi0 = a1[0], xi1 = a1[1];
    float4 yr0 = b0[0], yr1 = b0[1], yi0 = b1[0], yi1 = b1[1];
    Rreg[0]  = mkc(xr0.x, xi0.x); Rreg[2]  = mkc(xr0.y, xi0.y);
    Rreg[4]  = mkc(xr0.z, xi0.z); Rreg[6]  = mkc(xr0.w, xi0.w);
    Rreg[8]  = mkc(xr1.x, xi1.x); Rreg[10] = mkc(xr1.y, xi1.y);
    Rreg[12] = mkc(xr1.z, xi1.z); Rreg[14] = mkc(xr1.w, xi1.w);
    Rreg[1]  = mkc(yr0.x, yi0.x); Rreg[3]  = mkc(yr0.y, yi0.y);
    Rreg[5]  = mkc(yr0.z, yi0.z); Rreg[7]  = mkc(yr0.w, yi0.w);
    Rreg[9]  = mkc(yr1.x, yi1.x); Rreg[11] = mkc(yr1.y, yi1.y);
    Rreg[13] = mkc(yr1.z, yi1.z); Rreg[15] = mkc(yr1.w, yi1.w);
    #pragma unroll
    for (int q = 0; q < 16; ++q){
      rnp = fmaf(Rreg[q].x, Rreg[q].x, rnp);
      rnp = fmaf(Rreg[q].y, Rreg[q].y, rnp);
    }
  }
  // den = ||R[k,0]||_F^2
  float dp = 0.f;
  {
    const float* R0re = R_re + (size_t)(kk*64)*4096;
    const float* R0im = R_im + (size_t)(kk*64)*4096;
    for (int idx = tid; idx < 4096; idx += 256){
      float a = R0re[idx], c = R0im[idx];
      dp = fmaf(a, a, dp); dp = fmaf(c, c, dp);
    }
  }
  const float sqPt = sqrtf((float)PtA[0]);
  __syncthreads();

  const float Rnorm  = blockSum(rnp, sredm, tid);
  const float den    = blockSum(dp,  sredm, tid);
  const float invden = 1.f / den;

  // ---------- initial normalize ----------
  {
    cplx w0, w1;
    type2r<false>(sF, sW, tid, w0, w1);                 // FW = F@W
    float nn = w0.x*w0.x + w0.y*w0.y + w1.x*w1.x + w1.y*w1.y;
    float nrm2 = blockSum(nn, sredm, tid);
    float scale = sqPt / (sqrtf(nrm2) + 1e-12f);
    int n = tid & 63, w2 = tid >> 6;
    sT[(2*w2)*66 + n]   = mkc(w0.x*scale, w0.y*scale);  // scaled FW
    sT[(2*w2+1)*66 + n] = mkc(w1.x*scale, w1.y*scale);
    if (tid < 64){
      cplx wv = sW[(tid>>3)*9 + (tid&7)];
      sW[(tid>>3)*9 + (tid&7)] = mkc(wv.x*scale, wv.y*scale);
    }
  }
  __syncthreads();

  // ---------- rate_0 ----------
  { cplx pg = type3part(sF, sH, tid); scr[(tid>>6)*64 + (tid&63)] = pg; }
  __syncthreads();
  t3gather(sG, nullptr, nullptr, 1, scr, tid);
  __syncthreads();
  if (tid < 64){
    int m = tid >> 3, j = tid & 7;
    cplx a = mkc(0.f,0.f);
    #pragma unroll
    for (int r = 0; r < 8; ++r) cfmac(a, sG[r*9+m], sW[r*9+j]);   // t = g^H W
    sTM[m*9+j] = a;
  }
  __syncthreads();
  if (tid < 8){
    int m = tid; float t1 = 0.f;
    #pragma unroll
    for (int j = 0; j < 8; ++j){ cplx t = sTM[m*9+j]; t1 = fmaf(t.x,t.x,fmaf(t.y,t.y,t1)); }
    cplx td = sTM[m*9+m];
    float t2 = t1 - (td.x*td.x + td.y*td.y);
    sD2[m] = log2f((t1 + 1.f)/(t2 + 1.f));
  }
  __syncthreads();
  if (tid == 0){
    float rs = sD2[0]+sD2[1]+sD2[2]+sD2[3]+sD2[4]+sD2[5]+sD2[6]+sD2[7];
    atomicAdd(out_rates + bb*11 + 0, rs*0.125f);
  }
  // ---------- RF = R@F ----------
  computeRF(Rreg, sF, sRF, scr, tid);
  __syncthreads();
  // ---------- tau_0 ----------
  { cplx pk = type3part(sT, sT, tid); scr[(tid>>6)*64 + (tid&63)] = pk; }
  __syncthreads();
  t3gather(sG2, nullptr, nullptr, 1, scr, tid);
  __syncthreads();
  {
    cplx r0, r1;
    type2r<false>(sRF, sW, tid, r0, r1);                 // R@FW = RF@W
    int n = tid & 63, w2 = tid >> 6;
    cplx a = sT[(2*w2)*66 + n], b = sT[(2*w2+1)*66 + n];
    float dotp = a.x*r0.x + a.y*r0.y + b.x*r1.x + b.y*r1.y;
    float Tt  = blockSum(dotp, sredm, tid);
    float g2v = 0.f;
    if (tid < 64){ cplx g = sG2[(tid>>3)*9 + (tid&7)]; g2v = g.x*g.x + g.y*g.y; }
    float G2s = blockSum(g2v, sredm, tid);
    if (tid == 0){
      float num = G2s - 2.f*Tt + Rnorm;
      atomicAdd(out_taus + bb*11 + 0, num*invden*0.125f);
    }
  }

  // ================= main loop =================
  #pragma unroll 1
  for (int i = 0; i < 10; ++i){
    // ---- A: grad_F_com ----
    __syncthreads();
    if (tid < 64){                                        // sV[p][q] = V[q][p], V = W W^H
      int p = tid >> 3, q = tid & 7;
      cplx a = mkc(0.f,0.f);
      #pragma unroll
      for (int m = 0; m < 8; ++m) cfmac(a, sW[p*9+m], sW[q*9+m]);
      sV[p*9+q] = a;
    }
    __syncthreads();
    type2s<true>(sF, sV, sT, tid);                        // FV = F@V
    __syncthreads();
    {
      cplx pa = type3part(sH, sT, tid);                   // a1
      cplx pg = type3part(sF, sH, tid);                   // g
      int c = tid >> 6, pq = tid & 63;
      scr[(c*2+0)*64 + pq] = pa;
      scr[(c*2+1)*64 + pq] = pg;
    }
    __syncthreads();
    t3gather(sA1, sG, nullptr, 2, scr, tid);
    __syncthreads();
    if (tid < 8){                                         // s[m]
      cplx a = mkc(0.f,0.f);
      #pragma unroll
      for (int r = 0; r < 8; ++r) cfmac(a, sG[r*9+tid], sW[r*9+tid]);
      sSm[tid] = a;
    }
    if (tid < 64){                                        // Vg[m][r]
      int m = tid >> 3, r = tid & 7;
      cplx a = mkc(0.f,0.f);
      #pragma unroll
      for (int s2 = 0; s2 < 8; ++s2) cfma(a, sV[s2*9+r], sG[s2*9+m]);
      sTM[m*9+r] = a;
    }
    __syncthreads();
    if (tid < 8){
      int m = tid; float t1 = 0.f;
      #pragma unroll
      for (int r = 0; r < 8; ++r){
        cplx g = sG[r*9+m], vg = sTM[m*9+r];
        t1 = fmaf(g.x, vg.x, t1); t1 = fmaf(g.y, vg.y, t1);   // Re(conj(g)Vg)
      }
      cplx sm = sSm[m];
      float t2 = t1 - (sm.x*sm.x + sm.y*sm.y);
      sD1[m] = LN2F*(t1 + 1.f) + 1e-4f;
      sD2[m] = LN2F*(t2 + 1.f) + 1e-4f;
    }
    __syncthreads();
    if (tid < 64){                                        // c = a1/d1 - a2/d2
      int m = tid >> 3, r = tid & 7;
      cplx a1v = sA1[m*9+r];
      cplx sw = cmuljc(sSm[m], sW[r*9+m]);
      cplx a2v = mkc(a1v.x - sw.x, a1v.y - sw.y);
      float i1 = 1.f/sD1[m], i2 = 1.f/sD2[m];
      sC[m*9+r] = mkc(a1v.x*i1 - a2v.x*i2, a1v.y*i1 - a2v.y*i2);
    }
    __syncthreads();
    cplx f0, f1;
    type2r<false>(sH, sC, tid, f0, f1);                   // gFcom = sum_m H c

    // ---- B: grad_F_rad via RF; write P partial into own F-input slice ----
    { cplx px = type3part(sF, sT, tid); scr[(tid>>6)*64 + (tid&63)] = px; }  // X = F^H FV
    __syncthreads();
    t3gather(sX, nullptr, nullptr, 1, scr, tid);
    __syncthreads();
    cplx x0, x1, v0, v1;
    type2r<false>(sT, sX, tid, x0, x1);                   // FV @ X
    type2r<true >(sRF, sV, tid, v0, v1);                  // RF @ V
    {
      int n = tid & 63, w2 = tid >> 6;
      size_t base = kb*512;
      cplx P0 = mkc((f0.x - (x0.x - v0.x)*invden)*0.125f,
                    (f0.y - (x0.y - v0.y)*invden)*0.125f);
      cplx P1 = mkc((f1.x - (x1.x - v1.x)*invden)*0.125f,
                    (f1.y - (x1.y - v1.y)*invden)*0.125f);
      storePf(&PexRe[base + (2*w2)*64 + n],   P0.x);
      storePf(&PexIm[base + (2*w2)*64 + n],   P0.y);
      storePf(&PexRe[base + (2*w2+1)*64 + n], P1.x);
      storePf(&PexIm[base + (2*w2+1)*64 + n], P1.y);
    }
    groupBarrier(cnt, 8u*(2*i+1), tid);                   // write-ready

    // ---- D: F update + proj ----
    {
      const float step0 = step_g[i*9];
      #pragma unroll
      for (int o0 = 0; o0 < 2; ++o0){
        int o = tid + o0*256;
        int r = o >> 6, n = o & 63;
        cplx acc = mkc(0.f,0.f);
        #pragma unroll
        for (int kp = 0; kp < 8; ++kp){
          size_t idx = (size_t)(kp*64 + bb)*512 + r*64 + n;
          acc.x += loadPf(&PexRe[idx]);
          acc.y += loadPf(&PexIm[idx]);
        }
        cplx Fv = sF[r*66 + n];
        Fv.x = fmaf(step0, acc.x, Fv.x);
        Fv.y = fmaf(step0, acc.y, Fv.y);
        float mag = sqrtf(Fv.x*Fv.x + Fv.y*Fv.y);
        if (mag > 1e-12f){ Fv.x /= mag; Fv.y /= mag; } else { Fv = mkc(0.f,0.f); }
        sF[r*66 + n] = Fv;
      }
    }
    groupBarrier(cnt, 8u*(2*i+2), tid);                   // read-done (WAR guard)
    __syncthreads();
    // ---- E: RF = R @ F_new ----
    computeRF(Rreg, sF, sRF, scr, tid);
    __syncthreads();
    // ---- F: grad_W_com ----
    { cplx pg = type3part(sF, sH, tid); scr[(tid>>6)*64 + (tid&63)] = pg; }
    __syncthreads();
    t3gather(sG, nullptr, nullptr, 1, scr, tid);
    __syncthreads();
    if (tid < 64){                                        // u[m][j] = sum_r g conj(W)
      int m = tid >> 3, j = tid & 7;
      cplx a = mkc(0.f,0.f);
      #pragma unroll
      for (int r = 0; r < 8; ++r) cfmacj(a, sG[r*9+m], sW[r*9+j]);
      sU[m*9+j] = a;
    }
    __syncthreads();
    if (tid < 8){
      int m = tid; float tr = 0.f;
      #pragma unroll
      for (int j = 0; j < 8; ++j){ cplx u = sU[m*9+j]; tr = fmaf(u.x,u.x,fmaf(u.y,u.y,tr)); }
      sD1[m] = LN2F*(tr + 1.f);                           // no eps (source)
    }
    __syncthreads();
    if (tid < 64){
      int r = tid >> 3, m = tid & 7;
      cplx t = cmuljc(sG[r*9+m], sU[m*9+m]);
      float f = 0.125f / sD1[m];
      sGWC[r*9+m] = mkc(t.x*f, t.y*f);
    }
    __syncthreads();
    // ---- G: grad_W_rad + W update ----
    type2s<false>(sF, sW, sT, tid);                       // FW = F@W
    __syncthreads();
    {
      cplx pa = type3part(sF, sT, tid);                   // A  = F^H FW
      cplx pb = type3part(sT, sT, tid);                   // B2 = FW^H FW
      cplx pc = type3part(sF, sRF, tid);                  // C1 = F^H RF
      int c = tid >> 6, pq = tid & 63;
      scr[(c*3+0)*64 + pq] = pa;
      scr[(c*3+1)*64 + pq] = pb;
      scr[(c*3+2)*64 + pq] = pc;
    }
    __syncthreads();
    t3gather(sA2, sB2, sC1, 3, scr, tid);
    __syncthreads();
    {
      cplx ab = mkc(0.f,0.f), cw = mkc(0.f,0.f);
      int r = tid >> 3, m = tid & 7;
      if (tid < 64){
        #pragma unroll
        for (int m2 = 0; m2 < 8; ++m2) cfma(ab, sA2[r*9+m2], sB2[m2*9+m]);
        #pragma unroll
        for (int s2 = 0; s2 < 8; ++s2) cfma(cw, sC1[r*9+s2], sW[s2*9+m]);
      }
      __syncthreads();                                    // all reads of sW done
      if (tid < 64){
        float st = step_g[i*9 + 1 + kk];
        cplx gwc = sGWC[r*9+m];
        float fac = invden*0.125f;                        // = 0.5*gWrad scale
        float dx = gwc.x - (ab.x - cw.x)*fac;
        float dy = gwc.y - (ab.y - cw.y)*fac;
        cplx wv = sW[r*9+m];
        wv.x = fmaf(st, dx, wv.x);
        wv.y = fmaf(st, dy, wv.y);
        sW[r*9+m] = wv;
      }
    }
    __syncthreads();
    // ---- I: normalize ----
    {
      cplx w0, w1;
      type2r<false>(sF, sW, tid, w0, w1);
      float nn = w0.x*w0.x + w0.y*w0.y + w1.x*w1.x + w1.y*w1.y;
      float nrm2 = blockSum(nn, sredm, tid);
      float scale = sqPt / (sqrtf(nrm2) + 1e-12f);
      int n = tid & 63, w2 = tid >> 6;
      sT[(2*w2)*66 + n]   = mkc(w0.x*scale, w0.y*scale);  // scaled FW for tau
      sT[(2*w2+1)*66 + n] = mkc(w1.x*scale, w1.y*scale);
      if (tid < 64){
        cplx wv = sW[(tid>>3)*9 + (tid&7)];
        sW[(tid>>3)*9 + (tid&7)] = mkc(wv.x*scale, wv.y*scale);
      }
    }
    __syncthreads();
    // ---- J: sum_rate ----
    if (tid < 64){
      int m = tid >> 3, j = tid & 7;
      cplx a = mkc(0.f,0.f);
      #pragma unroll
      for (int r = 0; r < 8; ++r) cfmac(a, sG[r*9+m], sW[r*9+j]);
      sTM[m*9+j] = a;
    }
    __syncthreads();
    if (tid < 8){
      int m = tid; float t1 = 0.f;
      #pragma unroll
      for (int j = 0; j < 8; ++j){ cplx t = sTM[m*9+j]; t1 = fmaf(t.x,t.x,fmaf(t.y,t.y,t1)); }
      cplx td = sTM[m*9+m];
      float t2 = t1 - (td.x*td.x + td.y*td.y);
      sD2[m] = log2f((t1 + 1.f)/(t2 + 1.f));
    }
    __syncthreads();
    if (tid == 0){
      float rs = sD2[0]+sD2[1]+sD2[2]+sD2[3]+sD2[4]+sD2[5]+sD2[6]+sD2[7];
      atomicAdd(out_rates + bb*11 + (i+1), rs*0.125f);
    }
    // ---- K: beam err ----
    { cplx pk = type3part(sT, sT, tid); scr[(tid>>6)*64 + (tid&63)] = pk; }
    __syncthreads();
    t3gather(sG2, nullptr, nullptr, 1, scr, tid);
    __syncthreads();
    {
      cplx r0, r1;
      type2r<false>(sRF, sW, tid, r0, r1);                // RF @ W_final
      int n = tid & 63, w2 = tid >> 6;
      cplx a = sT[(2*w2)*66 + n], b = sT[(2*w2+1)*66 + n];
      float dotp = a.x*r0.x + a.y*r0.y + b.x*r1.x + b.y*r1.y;
      float Tt  = blockSum(dotp, sredm, tid);
      float g2v = 0.f;
      if (tid < 64){ cplx g = sG2[(tid>>3)*9 + (tid&7)]; g2v = g.x*g.x + g.y*g.y; }
      float G2s = blockSum(g2v, sredm, tid);
      if (tid == 0){
        float num = G2s - 2.f*Tt + Rnorm;
        atomicAdd(out_taus + bb*11 + (i+1), num*invden*0.125f);
      }
    }
  }

  // ---------- outputs (real parts only; d_out is float32) ----------
  __syncthreads();
  #pragma unroll
  for (int o0 = 0; o0 < 2; ++o0){
    int o = tid + o0*256;
    int n = o >> 3, r = o & 7;
    out_F[kb*512 + o] = sF[r*66 + n].x;
  }
  if (tid < 64){
    out_W[kb*64 + tid] = sW[(tid>>3)*9 + (tid&7)].x;
  }
}

extern "C" void kernel_launch(void* const* d_in, const int* in_sizes, int n_in,
                              void* d_out, int out_size, void* d_ws, size_t ws_size,
                              hipStream_t stream) {
  const float* H_re = (const float*)d_in[0];
  const float* H_im = (const float*)d_in[1];
  const float* R_re = (const float*)d_in[2];
  const float* R_im = (const float*)d_in[3];
  float* F_re = (float*)d_in[4];          // reused as P-exchange scratch
  float* F_im = (float*)d_in[5];
  const float* W_re = (const float*)d_in[6];
  const float* W_im = (const float*)d_in[7];
  const float* step = (const float*)d_in[8];
  const int*   PtA  = (const int*)d_in[9];
  float* out = (float*)d_out;

  // ws usage: only 64 per-b barrier counters. Stride 16 uints when room.
  unsigned* bcnt = (unsigned*)d_ws;
  int cstride = (ws_size >= 4096) ? 16 : 1;
  size_t cbytes = (size_t)64 * 4 * (size_t)cstride;
  if (cbytes > ws_size) cbytes = ws_size;

  hipMemsetAsync(d_ws, 0, cbytes, stream);               // zero barrier counters
  hipMemsetAsync(d_out, 0, 1408*sizeof(float), stream);  // zero rates+taus (atomic accum)

  pga_fused_kernel<<<dim3(512), dim3(256), 0, stream>>>(
      H_re, H_im, R_re, R_im, F_re, F_im, W_re, W_im,
      step, PtA, out, bcnt, cstride);
}

// Round 8
// 340.951 us; speedup vs baseline: 5.1576x; 5.1576x over previous
//
#include <hip/hip_runtime.h>

// PGA joint com/radar beamforming, K=8 B=64 M=8 NT=64 NRF=8, 10 iters.
// One persistent kernel: 512 blocks (one per (k,b)) x 256 threads, all
// co-resident (launch_bounds(256,2) -> 2 blocks/CU -> 512 slots == grid).
// OUTPUT (d_out, float32, 296320 elems): rates[64][11] | taus[64][11] |
//   Re(F)[K,B,64,8] | Re(W)[K,B,8,8].
// Cross-k F-gradient mean exchanged through DEAD INPUT slices, double-
// buffered: even iters use {F_re,F_im} slices, odd iters {H_re,H_im}
// (both dead after the initial load; harness restores d_in every launch).
// All exchange + barrier ops are RELAXED agent-scope atomics -> NO
// buffer_wbl2 / buffer_inv cache maintenance (R5's 1758us stall was the
// ACQUIRE poll loop invalidating L2 every iteration + threadfence flushes).
// Ordering: __syncthreads() drains all waves' vmcnt before the counter
// add; readers issue loads only after the post-poll __syncthreads().
// ONE barrier per iteration (10 total): WAR across the 2 buffers is
// guaranteed by barrier(i) (see proof in comments at groupBarrier).
// R held permanently in registers; RF = R@F computed once per iteration.

typedef float2 cplx;

#define LN2F 0.69314718055994530942f

__device__ __forceinline__ cplx mkc(float x, float y){ return make_float2(x, y); }

__device__ __forceinline__ void cfma (cplx& a, cplx b, cplx c){            // a += b*c
  a.x = fmaf(b.x, c.x, a.x); a.x = fmaf(-b.y, c.y, a.x);
  a.y = fmaf(b.x, c.y, a.y); a.y = fmaf( b.y, c.x, a.y);
}
__device__ __forceinline__ void cfmac(cplx& a, cplx b, cplx c){            // a += conj(b)*c
  a.x = fmaf(b.x, c.x, a.x); a.x = fmaf( b.y, c.y, a.x);
  a.y = fmaf(b.x, c.y, a.y); a.y = fmaf(-b.y, c.x, a.y);
}
__device__ __forceinline__ void cfmacj(cplx& a, cplx b, cplx c){           // a += b*conj(c)
  a.x = fmaf(b.x, c.x, a.x); a.x = fmaf( b.y, c.y, a.x);
  a.y = fmaf(-b.x, c.y, a.y); a.y = fmaf( b.y, c.x, a.y);
}
__device__ __forceinline__ cplx cmuljc(cplx b, cplx c){                    // b*conj(c)
  return mkc(b.x*c.x + b.y*c.y, b.y*c.x - b.x*c.y);
}

// RELAXED agent-scope 8B ops for the cross-XCD P exchange (coherent at LLC,
// no cache-maintenance instructions emitted)
__device__ __forceinline__ void storeP(float2* p, cplx v){
  union { cplx f; unsigned long long u; } cv; cv.f = v;
  __hip_atomic_store((unsigned long long*)p, cv.u, __ATOMIC_RELAXED, __HIP_MEMORY_SCOPE_AGENT);
}
__device__ __forceinline__ cplx loadP(const float2* p){
  union { cplx f; unsigned long long u; } cv;
  cv.u = __hip_atomic_load((const unsigned long long*)p, __ATOMIC_RELAXED, __HIP_MEMORY_SCOPE_AGENT);
  return cv.f;
}

__device__ __forceinline__ float blockSum(float v, float* sred, int tid){
  #pragma unroll
  for (int off = 32; off > 0; off >>= 1) v += __shfl_down(v, off, 64);
  __syncthreads();                       // protect sred reuse
  if ((tid & 63) == 0) sred[tid >> 6] = v;
  __syncthreads();
  return sred[0] + sred[1] + sred[2] + sred[3];
}

// OUT[q][n] = sum_s IN[s][n] * (TR ? SM[q][s] : SM[s][q]); q = 2w,2w+1, n = lane
template<bool TR>
__device__ __forceinline__ void type2r(const cplx* __restrict__ IN, const cplx* __restrict__ SM,
                                       int tid, cplx& o0, cplx& o1){
  const int n = tid & 63, w = tid >> 6;
  const int q0 = 2*w, q1 = 2*w + 1;
  cplx a = mkc(0.f,0.f), b = mkc(0.f,0.f);
  #pragma unroll
  for (int s = 0; s < 8; ++s){
    cplx in = IN[s*66 + n];
    cplx m0 = TR ? SM[q0*9 + s] : SM[s*9 + q0];
    cplx m1 = TR ? SM[q1*9 + s] : SM[s*9 + q1];
    cfma(a, in, m0);
    cfma(b, in, m1);
  }
  o0 = a; o1 = b;
}

template<bool TR>
__device__ __forceinline__ void type2s(const cplx* IN, const cplx* SM, cplx* OUT, int tid){
  cplx o0, o1;
  type2r<TR>(IN, SM, tid, o0, o1);
  const int n = tid & 63, w = tid >> 6;
  OUT[(2*w)*66 + n]   = o0;
  OUT[(2*w+1)*66 + n] = o1;
}

// partial of O[p][q] = sum_n conj(P1[p][n]) * P2[q][n] over n in [16c,16c+16)
__device__ __forceinline__ cplx type3part(const cplx* __restrict__ P1, const cplx* __restrict__ P2, int tid){
  const int p = (tid >> 3) & 7, q = tid & 7, c = tid >> 6;
  const int n0 = c * 16;
  cplx a = mkc(0.f,0.f);
  #pragma unroll
  for (int nn = 0; nn < 16; ++nn){
    cfmac(a, P1[p*66 + n0 + nn], P2[q*66 + n0 + nn]);
  }
  return a;
}

__device__ __forceinline__ void t3gather(cplx* d0, cplx* d1, cplx* d2, int nops,
                                         const cplx* scr, int tid){
  if (tid < nops*64){
    int op = tid >> 6, pq = tid & 63;
    cplx a = scr[(0*nops+op)*64 + pq];
    cplx b = scr[(1*nops+op)*64 + pq];
    cplx c = scr[(2*nops+op)*64 + pq];
    cplx d = scr[(3*nops+op)*64 + pq];
    cplx r = mkc(a.x+b.x+c.x+d.x, a.y+b.y+c.y+d.y);
    cplx* dst = (op == 0) ? d0 : (op == 1) ? d1 : d2;
    dst[(pq>>3)*9 + (pq&7)] = r;
  }
}

// RF = R @ F using register-resident R tiles. Each thread (wave w, lane l):
// rows (l&31, (l&31)+32), j in [16w + 8*(l>>5), +8). scr >= 1152 cplx.
__device__ __forceinline__ void computeRF(const cplx* Rreg, const cplx* sF_, cplx* sRF_,
                                          cplx* scr, int tid){
  const int l = tid & 63, w = tid >> 6;
  const int half = l >> 5;
  const int j0 = w*16 + half*8;
  cplx acc[16];
  #pragma unroll
  for (int q = 0; q < 16; ++q) acc[q] = mkc(0.f,0.f);
  #pragma unroll
  for (int jj = 0; jj < 8; ++jj){
    const int j = j0 + jj;
    cplx Ra = Rreg[2*jj], Rb = Rreg[2*jj+1];
    #pragma unroll
    for (int r = 0; r < 8; ++r){
      cplx f = sF_[r*66 + j];              // wave-broadcast (2 addrs) - free
      cfma(acc[r],   Ra, f);
      cfma(acc[8+r], Rb, f);
    }
  }
  #pragma unroll
  for (int q = 0; q < 16; ++q){            // combine j-halves (lanes l <-> l^32)
    acc[q].x += __shfl_xor(acc[q].x, 32, 64);
    acc[q].y += __shfl_xor(acc[q].y, 32, 64);
  }
  const int row = (half == 0) ? (l & 31) : ((l & 31) + 32);
  const int off = half ? 8 : 0;
  __syncthreads();                         // protect scr
  if (w < 2){
    #pragma unroll
    for (int r = 0; r < 8; ++r) scr[w*576 + row*9 + r] = acc[off + r];
  }
  __syncthreads();
  if (w >= 2){
    const int base = (w-2)*576 + row*9;
    #pragma unroll
    for (int r = 0; r < 8; ++r){
      cplx t = scr[base + r];
      t.x += acc[off + r].x; t.y += acc[off + r].y;
      scr[base + r] = t;
    }
  }
  __syncthreads();
  #pragma unroll
  for (int o0 = 0; o0 < 2; ++o0){
    const int o = tid + o0*256;
    const int r = o >> 6, n = o & 63;
    cplx a = scr[n*9 + r], b = scr[576 + n*9 + r];
    sRF_[r*66 + n] = mkc(a.x + b.x, a.y + b.y);
  }
}

// per-b barrier among the 8 k-blocks (monotonic counter, RELAXED-only).
// Correctness: the __syncthreads() before the add forces the compiler's
// full s_waitcnt (vmcnt drain) in EVERY wave, so all agent-scope P stores
// of this block have completed at the LLC before the counter bumps.
// Readers only issue their loads after the post-poll __syncthreads().
// WAR across iterations is safe with ONE barrier because a block writes
// buf[(i+1)&1] only after passing barrier(i), which requires all peers to
// have arrived at barrier(i) -- which in program order is after their
// reads of buf[(i-1)&1] (the same buffer).
__device__ __forceinline__ void groupBarrier(unsigned* cnt, unsigned target, int tid){
  __syncthreads();
  if (tid == 0){
    __hip_atomic_fetch_add(cnt, 1u, __ATOMIC_RELAXED, __HIP_MEMORY_SCOPE_AGENT);
    while (__hip_atomic_load(cnt, __ATOMIC_RELAXED, __HIP_MEMORY_SCOPE_AGENT) < target){
      __builtin_amdgcn_s_sleep(1);
    }
  }
  __syncthreads();
}

__global__ __launch_bounds__(256, 2)
void pga_fused_kernel(float* __restrict__ H_re, float* __restrict__ H_im,
                      const float* __restrict__ R_re, const float* __restrict__ R_im,
                      float* __restrict__ F_re, float* __restrict__ F_im,
                      const float* __restrict__ W_re, const float* __restrict__ W_im,
                      const float* __restrict__ step_g, const int* __restrict__ PtA,
                      float* __restrict__ out, unsigned* __restrict__ bcnt,
                      int cstride)
{
  const int bid = blockIdx.x;
  const int kk = bid >> 6;             // subcarrier
  const int bb = bid & 63;             // batch (same-b blocks 64 apart -> same XCD under %8 round-robin)
  const int tid = threadIdx.x;
  const int l = tid & 63, w = tid >> 6;
  const size_t kb = (size_t)(kk*64 + bb);

  __shared__ cplx sF [528];            // [8][66]: sF[r][n] = F[n][r]
  __shared__ cplx sT [528];            // FV / FW temp
  __shared__ cplx sRF[528];            // R@F
  __shared__ cplx sH [528];            // H[m][n]
  __shared__ cplx sml[13*72];          // 8x8 mats, [p*9+q]
  __shared__ cplx scr[1152];           // reductions
  __shared__ float sD1[8], sD2[8], sredm[8];
  __shared__ cplx sSm[8];

  cplx* sW  = sml + 0*72;
  cplx* sV  = sml + 1*72;
  cplx* sG  = sml + 2*72;   // g stored transposed: sG[r*9+m] = g[m][r]
  cplx* sA1 = sml + 3*72;
  cplx* sX  = sml + 4*72;
  cplx* sC  = sml + 5*72;
  cplx* sU  = sml + 6*72;
  cplx* sGWC= sml + 7*72;
  cplx* sTM = sml + 8*72;
  cplx* sA2 = sml + 9*72;
  cplx* sB2 = sml + 10*72;
  cplx* sC1 = sml + 11*72;
  cplx* sG2 = sml + 12*72;

  float* out_rates = out;              // [64][11]
  float* out_taus  = out + 704;       // [64][11]
  float* out_F = out + 1408;          // Re(F) [K,B,64,8]
  float* out_W = out + 1408 + 262144; // Re(W) [K,B,8,8]

  unsigned* cnt = bcnt + bb*cstride;

  const float* Hre = H_re + kb*512;
  const float* Him = H_im + kb*512;
  const float* Fre = F_re + kb*512;
  const float* Fim = F_im + kb*512;
  const float* Wre = W_re + kb*64;
  const float* Wim = W_im + kb*64;
  const float* Rre = R_re + kb*4096;
  const float* Rim = R_im + kb*4096;

  // ---------- loads ----------
  #pragma unroll
  for (int o0 = 0; o0 < 2; ++o0){
    int o = tid + o0*256;
    int m = o >> 6, n = o & 63;
    sH[m*66 + n] = mkc(Hre[m*64 + n], Him[m*64 + n]);
  }
  #pragma unroll
  for (int o0 = 0; o0 < 2; ++o0){
    int o = tid + o0*256;
    int n = o >> 3, r = o & 7;
    float fr = Fre[n*8 + r], fi = Fim[n*8 + r];
    float mag = sqrtf(fr*fr + fi*fi);
    cplx v = (mag > 1e-12f) ? mkc(fr/mag, fi/mag) : mkc(0.f,0.f);   // proj_unit
    sF[r*66 + n] = v;
  }
  if (tid < 64) sW[(tid>>3)*9 + (tid&7)] = mkc(Wre[tid], Wim[tid]);

  // R tiles -> registers, + ||R_kb||^2 partial
  cplx Rreg[16];
  float rnp = 0.f;
  {
    const int rA = l & 31, rB = rA + 32;
    const int j0 = w*16 + (l >> 5)*8;
    const float4* a0 = (const float4*)(Rre + rA*64 + j0);
    const float4* a1 = (const float4*)(Rim + rA*64 + j0);
    const float4* b0 = (const float4*)(Rre + rB*64 + j0);
    const float4* b1 = (const float4*)(Rim + rB*64 + j0);
    float4 xr0 = a0[0], xr1 = a0[1], xi0 = a1[0], xi1 = a1[1];
    float4 yr0 = b0[0], yr1 = b0[1], yi0 = b1[0], yi1 = b1[1];
    Rreg[0]  = mkc(xr0.x, xi0.x); Rreg[2]  = mkc(xr0.y, xi0.y);
    Rreg[4]  = mkc(xr0.z, xi0.z); Rreg[6]  = mkc(xr0.w, xi0.w);
    Rreg[8]  = mkc(xr1.x, xi1.x); Rreg[10] = mkc(xr1.y, xi1.y);
    Rreg[12] = mkc(xr1.z, xi1.z); Rreg[14] = mkc(xr1.w, xi1.w);
    Rreg[1]  = mkc(yr0.x, yi0.x); Rreg[3]  = mkc(yr0.y, yi0.y);
    Rreg[5]  = mkc(yr0.z, yi0.z); Rreg[7]  = mkc(yr0.w, yi0.w);
    Rreg[9]  = mkc(yr1.x, yi1.x); Rreg[11] = mkc(yr1.y, yi1.y);
    Rreg[13] = mkc(yr1.z, yi1.z); Rreg[15] = mkc(yr1.w, yi1.w);
    #pragma unroll
    for (int q = 0; q < 16; ++q){
      rnp = fmaf(Rreg[q].x, Rreg[q].x, rnp);
      rnp = fmaf(Rreg[q].y, Rreg[q].y, rnp);
    }
  }
  // den = ||R[k,0]||_F^2
  float dp = 0.f;
  {
    const float* R0re = R_re + (size_t)(kk*64)*4096;
    const float* R0im = R_im + (size_t)(kk*64)*4096;
    for (int idx = tid; idx < 4096; idx += 256){
      float a = R0re[idx], c = R0im[idx];
      dp = fmaf(a, a, dp); dp = fmaf(c, c, dp);
    }
  }
  const float sqPt = sqrtf((float)PtA[0]);
  __syncthreads();

  const float Rnorm  = blockSum(rnp, sredm, tid);
  const float den    = blockSum(dp,  sredm, tid);
  const float invden = 1.f / den;

  // ---------- initial normalize ----------
  {
    cplx w0, w1;
    type2r<false>(sF, sW, tid, w0, w1);                 // FW = F@W
    float nn = w0.x*w0.x + w0.y*w0.y + w1.x*w1.x + w1.y*w1.y;
    float nrm2 = blockSum(nn, sredm, tid);
    float scale = sqPt / (sqrtf(nrm2) + 1e-12f);
    int n = tid & 63, w2 = tid >> 6;
    sT[(2*w2)*66 + n]   = mkc(w0.x*scale, w0.y*scale);  // scaled FW
    sT[(2*w2+1)*66 + n] = mkc(w1.x*scale, w1.y*scale);
    if (tid < 64){
      cplx wv = sW[(tid>>3)*9 + (tid&7)];
      sW[(tid>>3)*9 + (tid&7)] = mkc(wv.x*scale, wv.y*scale);
    }
  }
  __syncthreads();

  // ---------- rate_0 ----------
  { cplx pg = type3part(sF, sH, tid); scr[(tid>>6)*64 + (tid&63)] = pg; }
  __syncthreads();
  t3gather(sG, nullptr, nullptr, 1, scr, tid);
  __syncthreads();
  if (tid < 64){
    int m = tid >> 3, j = tid & 7;
    cplx a = mkc(0.f,0.f);
    #pragma unroll
    for (int r = 0; r < 8; ++r) cfmac(a, sG[r*9+m], sW[r*9+j]);   // t = g^H W
    sTM[m*9+j] = a;
  }
  __syncthreads();
  if (tid < 8){
    int m = tid; float t1 = 0.f;
    #pragma unroll
    for (int j = 0; j < 8; ++j){ cplx t = sTM[m*9+j]; t1 = fmaf(t.x,t.x,fmaf(t.y,t.y,t1)); }
    cplx td = sTM[m*9+m];
    float t2 = t1 - (td.x*td.x + td.y*td.y);
    sD2[m] = log2f((t1 + 1.f)/(t2 + 1.f));
  }
  __syncthreads();
  if (tid == 0){
    float rs = sD2[0]+sD2[1]+sD2[2]+sD2[3]+sD2[4]+sD2[5]+sD2[6]+sD2[7];
    atomicAdd(out_rates + bb*11 + 0, rs*0.125f);
  }
  // ---------- RF = R@F ----------
  computeRF(Rreg, sF, sRF, scr, tid);
  __syncthreads();
  // ---------- tau_0 ----------
  { cplx pk = type3part(sT, sT, tid); scr[(tid>>6)*64 + (tid&63)] = pk; }
  __syncthreads();
  t3gather(sG2, nullptr, nullptr, 1, scr, tid);
  __syncthreads();
  {
    cplx r0, r1;
    type2r<false>(sRF, sW, tid, r0, r1);                 // R@FW = RF@W
    int n = tid & 63, w2 = tid >> 6;
    cplx a = sT[(2*w2)*66 + n], b = sT[(2*w2+1)*66 + n];
    float dotp = a.x*r0.x + a.y*r0.y + b.x*r1.x + b.y*r1.y;
    float Tt  = blockSum(dotp, sredm, tid);
    float g2v = 0.f;
    if (tid < 64){ cplx g = sG2[(tid>>3)*9 + (tid&7)]; g2v = g.x*g.x + g.y*g.y; }
    float G2s = blockSum(g2v, sredm, tid);
    if (tid == 0){
      float num = G2s - 2.f*Tt + Rnorm;
      atomicAdd(out_taus + bb*11 + 0, num*invden*0.125f);
    }
  }

  // ================= main loop =================
  #pragma unroll 1
  for (int i = 0; i < 10; ++i){
    // ---- A: grad_F_com ----
    __syncthreads();
    if (tid < 64){                                        // sV[p][q] = V[q][p], V = W W^H
      int p = tid >> 3, q = tid & 7;
      cplx a = mkc(0.f,0.f);
      #pragma unroll
      for (int m = 0; m < 8; ++m) cfmac(a, sW[p*9+m], sW[q*9+m]);
      sV[p*9+q] = a;
    }
    __syncthreads();
    type2s<true>(sF, sV, sT, tid);                        // FV = F@V
    __syncthreads();
    {
      cplx pa = type3part(sH, sT, tid);                   // a1
      cplx pg = type3part(sF, sH, tid);                   // g
      int c = tid >> 6, pq = tid & 63;
      scr[(c*2+0)*64 + pq] = pa;
      scr[(c*2+1)*64 + pq] = pg;
    }
    __syncthreads();
    t3gather(sA1, sG, nullptr, 2, scr, tid);
    __syncthreads();
    if (tid < 8){                                         // s[m]
      cplx a = mkc(0.f,0.f);
      #pragma unroll
      for (int r = 0; r < 8; ++r) cfmac(a, sG[r*9+tid], sW[r*9+tid]);
      sSm[tid] = a;
    }
    if (tid < 64){                                        // Vg[m][r]
      int m = tid >> 3, r = tid & 7;
      cplx a = mkc(0.f,0.f);
      #pragma unroll
      for (int s2 = 0; s2 < 8; ++s2) cfma(a, sV[s2*9+r], sG[s2*9+m]);
      sTM[m*9+r] = a;
    }
    __syncthreads();
    if (tid < 8){
      int m = tid; float t1 = 0.f;
      #pragma unroll
      for (int r = 0; r < 8; ++r){
        cplx g = sG[r*9+m], vg = sTM[m*9+r];
        t1 = fmaf(g.x, vg.x, t1); t1 = fmaf(g.y, vg.y, t1);   // Re(conj(g)Vg)
      }
      cplx sm = sSm[m];
      float t2 = t1 - (sm.x*sm.x + sm.y*sm.y);
      sD1[m] = LN2F*(t1 + 1.f) + 1e-4f;
      sD2[m] = LN2F*(t2 + 1.f) + 1e-4f;
    }
    __syncthreads();
    if (tid < 64){                                        // c = a1/d1 - a2/d2
      int m = tid >> 3, r = tid & 7;
      cplx a1v = sA1[m*9+r];
      cplx sw = cmuljc(sSm[m], sW[r*9+m]);
      cplx a2v = mkc(a1v.x - sw.x, a1v.y - sw.y);
      float i1 = 1.f/sD1[m], i2 = 1.f/sD2[m];
      sC[m*9+r] = mkc(a1v.x*i1 - a2v.x*i2, a1v.y*i1 - a2v.y*i2);
    }
    __syncthreads();
    cplx f0, f1;
    type2r<false>(sH, sC, tid, f0, f1);                   // gFcom = sum_m H c

    // ---- B: grad_F_rad via RF; write P into own dbuf slice ----
    { cplx px = type3part(sF, sT, tid); scr[(tid>>6)*64 + (tid&63)] = px; }  // X = F^H FV
    __syncthreads();
    t3gather(sX, nullptr, nullptr, 1, scr, tid);
    __syncthreads();
    cplx x0, x1, v0, v1;
    type2r<false>(sT, sX, tid, x0, x1);                   // FV @ X
    type2r<true >(sRF, sV, tid, v0, v1);                  // RF @ V
    {
      int n = tid & 63, w2 = tid >> 6;
      // P element e = r*64+n packed as float2: e<256 -> lo slice, else hi
      float2* lo = (float2*)((i & 1) ? H_re : F_re) + kb*256;
      float2* hi = (float2*)((i & 1) ? H_im : F_im) + kb*256;
      cplx P0 = mkc((f0.x - (x0.x - v0.x)*invden)*0.125f,
                    (f0.y - (x0.y - v0.y)*invden)*0.125f);
      cplx P1 = mkc((f1.x - (x1.x - v1.x)*invden)*0.125f,
                    (f1.y - (x1.y - v1.y)*invden)*0.125f);
      int e0 = (2*w2)*64 + n;                             // e1 = e0 + 64
      if (e0 < 256){ storeP(lo + e0, P0); storeP(lo + e0 + 64, P1); }
      else         { storeP(hi + e0 - 256, P0); storeP(hi + e0 - 192, P1); }
    }
    groupBarrier(cnt, 8u*(i+1), tid);                     // single barrier/iter

    // ---- D: F update + proj ----
    {
      const float step0 = step_g[i*9];
      const float2* baseLo = (const float2*)((i & 1) ? H_re : F_re);
      const float2* baseHi = (const float2*)((i & 1) ? H_im : F_im);
      #pragma unroll
      for (int o0 = 0; o0 < 2; ++o0){
        int o = tid + o0*256;                             // element e = o
        int r = o >> 6, n = o & 63;
        const float2* base = (o < 256) ? baseLo : baseHi;
        int eloc = o & 255;
        cplx acc = mkc(0.f,0.f);
        #pragma unroll
        for (int kp = 0; kp < 8; ++kp){
          cplx pv = loadP(base + (size_t)(kp*64 + bb)*256 + eloc);
          acc.x += pv.x; acc.y += pv.y;
        }
        cplx Fv = sF[r*66 + n];
        Fv.x = fmaf(step0, acc.x, Fv.x);
        Fv.y = fmaf(step0, acc.y, Fv.y);
        float mag = sqrtf(Fv.x*Fv.x + Fv.y*Fv.y);
        if (mag > 1e-12f){ Fv.x /= mag; Fv.y /= mag; } else { Fv = mkc(0.f,0.f); }
        sF[r*66 + n] = Fv;
      }
    }
    __syncthreads();
    // ---- E: RF = R @ F_new ----
    computeRF(Rreg, sF, sRF, scr, tid);
    __syncthreads();
    // ---- F: grad_W_com ----
    { cplx pg = type3part(sF, sH, tid); scr[(tid>>6)*64 + (tid&63)] = pg; }
    __syncthreads();
    t3gather(sG, nullptr, nullptr, 1, scr, tid);
    __syncthreads();
    if (tid < 64){                                        // u[m][j] = sum_r g conj(W)
      int m = tid >> 3, j = tid & 7;
      cplx a = mkc(0.f,0.f);
      #pragma unroll
      for (int r = 0; r < 8; ++r) cfmacj(a, sG[r*9+m], sW[r*9+j]);
      sU[m*9+j] = a;
    }
    __syncthreads();
    if (tid < 8){
      int m = tid; float tr = 0.f;
      #pragma unroll
      for (int j = 0; j < 8; ++j){ cplx u = sU[m*9+j]; tr = fmaf(u.x,u.x,fmaf(u.y,u.y,tr)); }
      sD1[m] = LN2F*(tr + 1.f);                           // no eps (source)
    }
    __syncthreads();
    if (tid < 64){
      int r = tid >> 3, m = tid & 7;
      cplx t = cmuljc(sG[r*9+m], sU[m*9+m]);
      float f = 0.125f / sD1[m];
      sGWC[r*9+m] = mkc(t.x*f, t.y*f);
    }
    __syncthreads();
    // ---- G: grad_W_rad + W update ----
    type2s<false>(sF, sW, sT, tid);                       // FW = F@W
    __syncthreads();
    {
      cplx pa = type3part(sF, sT, tid);                   // A  = F^H FW
      cplx pb = type3part(sT, sT, tid);                   // B2 = FW^H FW
      cplx pc = type3part(sF, sRF, tid);                  // C1 = F^H RF
      int c = tid >> 6, pq = tid & 63;
      scr[(c*3+0)*64 + pq] = pa;
      scr[(c*3+1)*64 + pq] = pb;
      scr[(c*3+2)*64 + pq] = pc;
    }
    __syncthreads();
    t3gather(sA2, sB2, sC1, 3, scr, tid);
    __syncthreads();
    {
      cplx ab = mkc(0.f,0.f), cw = mkc(0.f,0.f);
      int r = tid >> 3, m = tid & 7;
      if (tid < 64){
        #pragma unroll
        for (int m2 = 0; m2 < 8; ++m2) cfma(ab, sA2[r*9+m2], sB2[m2*9+m]);
        #pragma unroll
        for (int s2 = 0; s2 < 8; ++s2) cfma(cw, sC1[r*9+s2], sW[s2*9+m]);
      }
      __syncthreads();                                    // all reads of sW done
      if (tid < 64){
        float st = step_g[i*9 + 1 + kk];
        cplx gwc = sGWC[r*9+m];
        float fac = invden*0.125f;                        // = 0.5*gWrad scale
        float dx = gwc.x - (ab.x - cw.x)*fac;
        float dy = gwc.y - (ab.y - cw.y)*fac;
        cplx wv = sW[r*9+m];
        wv.x = fmaf(st, dx, wv.x);
        wv.y = fmaf(st, dy, wv.y);
        sW[r*9+m] = wv;
      }
    }
    __syncthreads();
    // ---- I: normalize ----
    {
      cplx w0, w1;
      type2r<false>(sF, sW, tid, w0, w1);
      float nn = w0.x*w0.x + w0.y*w0.y + w1.x*w1.x + w1.y*w1.y;
      float nrm2 = blockSum(nn, sredm, tid);
      float scale = sqPt / (sqrtf(nrm2) + 1e-12f);
      int n = tid & 63, w2 = tid >> 6;
      sT[(2*w2)*66 + n]   = mkc(w0.x*scale, w0.y*scale);  // scaled FW for tau
      sT[(2*w2+1)*66 + n] = mkc(w1.x*scale, w1.y*scale);
      if (tid < 64){
        cplx wv = sW[(tid>>3)*9 + (tid&7)];
        sW[(tid>>3)*9 + (tid&7)] = mkc(wv.x*scale, wv.y*scale);
      }
    }
    __syncthreads();
    // ---- J: sum_rate ----
    if (tid < 64){
      int m = tid >> 3, j = tid & 7;
      cplx a = mkc(0.f,0.f);
      #pragma unroll
      for (int r = 0; r < 8; ++r) cfmac(a, sG[r*9+m], sW[r*9+j]);
      sTM[m*9+j] = a;
    }
    __syncthreads();
    if (tid < 8){
      int m = tid; float t1 = 0.f;
      #pragma unroll
      for (int j = 0; j < 8; ++j){ cplx t = sTM[m*9+j]; t1 = fmaf(t.x,t.x,fmaf(t.y,t.y,t1)); }
      cplx td = sTM[m*9+m];
      float t2 = t1 - (td.x*td.x + td.y*td.y);
      sD2[m] = log2f((t1 + 1.f)/(t2 + 1.f));
    }
    __syncthreads();
    if (tid == 0){
      float rs = sD2[0]+sD2[1]+sD2[2]+sD2[3]+sD2[4]+sD2[5]+sD2[6]+sD2[7];
      atomicAdd(out_rates + bb*11 + (i+1), rs*0.125f);
    }
    // ---- K: beam err ----
    { cplx pk = type3part(sT, sT, tid); scr[(tid>>6)*64 + (tid&63)] = pk; }
    __syncthreads();
    t3gather(sG2, nullptr, nullptr, 1, scr, tid);
    __syncthreads();
    {
      cplx r0, r1;
      type2r<false>(sRF, sW, tid, r0, r1);                // RF @ W_final
      int n = tid & 63, w2 = tid >> 6;
      cplx a = sT[(2*w2)*66 + n], b = sT[(2*w2+1)*66 + n];
      float dotp = a.x*r0.x + a.y*r0.y + b.x*r1.x + b.y*r1.y;
      float Tt  = blockSum(dotp, sredm, tid);
      float g2v = 0.f;
      if (tid < 64){ cplx g = sG2[(tid>>3)*9 + (tid&7)]; g2v = g.x*g.x + g.y*g.y; }
      float G2s = blockSum(g2v, sredm, tid);
      if (tid == 0){
        float num = G2s - 2.f*Tt + Rnorm;
        atomicAdd(out_taus + bb*11 + (i+1), num*invden*0.125f);
      }
    }
  }

  // ---------- outputs (real parts only; d_out is float32) ----------
  __syncthreads();
  #pragma unroll
  for (int o0 = 0; o0 < 2; ++o0){
    int o = tid + o0*256;
    int n = o >> 3, r = o & 7;
    out_F[kb*512 + o] = sF[r*66 + n].x;
  }
  if (tid < 64){
    out_W[kb*64 + tid] = sW[(tid>>3)*9 + (tid&7)].x;
  }
}

extern "C" void kernel_launch(void* const* d_in, const int* in_sizes, int n_in,
                              void* d_out, int out_size, void* d_ws, size_t ws_size,
                              hipStream_t stream) {
  float* H_re = (float*)d_in[0];          // slices reused as P-exchange dbuf B
  float* H_im = (float*)d_in[1];
  const float* R_re = (const float*)d_in[2];
  const float* R_im = (const float*)d_in[3];
  float* F_re = (float*)d_in[4];          // slices reused as P-exchange dbuf A
  float* F_im = (float*)d_in[5];
  const float* W_re = (const float*)d_in[6];
  const float* W_im = (const float*)d_in[7];
  const float* step = (const float*)d_in[8];
  const int*   PtA  = (const int*)d_in[9];
  float* out = (float*)d_out;

  // ws usage: only 64 per-b barrier counters. Stride 16 uints when room.
  unsigned* bcnt = (unsigned*)d_ws;
  int cstride = (ws_size >= 4096) ? 16 : 1;
  size_t cbytes = (size_t)64 * 4 * (size_t)cstride;
  if (cbytes > ws_size) cbytes = ws_size;

  hipMemsetAsync(d_ws, 0, cbytes, stream);               // zero barrier counters
  hipMemsetAsync(d_out, 0, 1408*sizeof(float), stream);  // zero rates+taus (atomic accum)

  pga_fused_kernel<<<dim3(512), dim3(256), 0, stream>>>(
      H_re, H_im, R_re, R_im, F_re, F_im, W_re, W_im,
      step, PtA, out, bcnt, cstride);
}